// Round 7
// baseline (1462.974 us; speedup 1.0000x reference)
//
#include <hip/hip_runtime.h>

// Neighbor search: M=N=12288, DIM=3.
// d_out layout (float32, flat, return order):
//   [0 .. M]                row_splits (M+1 counts-prefix as floats)
//   [M+1 .. M+1+M*N)        mask (0.0 / 1.0)
//   [M+1+M*N .. +2*M*N)     weights (d2 if mask else 0)
//
// R1-R5 post-mortem: every kernel that carries the dense 1.208 GB store
// stream plateaus at 2.5-4.3 TB/s effective regardless of structure
// (row-owned / LDS / aligned float4 / phase-rotated / linear sweep), while
// pure-store fillBuffer does 6.2 TB/s on the same buffer. R6: split roles.
//   A) zero_kernel: fillBuffer-clone (grid-stride lane-consecutive dwordx4,
//      nontemporal) zeroes mask+weights at fill speed.
//   B) sparse_kernel: compute-only, 8 rows/block, LDS-staged data, stores
//      ONLY the ~0.26% in-radius elements (~3 MB) under execz-skipped
//      branches; per-row counts without atomics.
//   C) scan_kernel: row_splits.
// R6 fix: __builtin_nontemporal_store needs a native vector type, not
// HIP_vector_type -> use ext_vector_type(4) float.
//
// Numerics (unchanged since R1, absmax 256-1024 vs np ref, threshold 7004):
//   sq = (x*x + y*y) + z*z               (each op rounded)
//   dot = fma(q2,d2, fma(q1,d1, q0*d0))  (sgemm ascending-k chain)
//   v = fma(-2, dot, sq_q+sq_d)          (== (sq_q+sq_d) - 2*dot exactly)
//   v = max(v,0); mask = v <= r*r

#define ZGRID 2048
#define RPB 8      // rows (queries) per block
#define DTILE 1024 // data points per LDS tile: 12 KB

typedef float floatx4 __attribute__((ext_vector_type(4)));

// Zero out[start .. start+count) mimicking __amd_rocclr_fillBufferAligned:
// grid-stride, lane-consecutive float4 nontemporal stores (1 KB/wave/instr).
__global__ __launch_bounds__(256) void zero_kernel(
    float* __restrict__ out, long long start, long long count)
{
    const int head = (int)((4 - (start & 3)) & 3);     // scalars to 16B align
    const long long qstart = start + head;
    const long long K = (count - head) >> 2;           // whole float4s
    const int tail = (int)((count - head) & 3);

    floatx4* __restrict__ base = reinterpret_cast<floatx4*>(out + qstart);
    const floatx4 z = {0.f, 0.f, 0.f, 0.f};
    const long long stride = (long long)gridDim.x * 256;
    for (long long i = (long long)blockIdx.x * 256 + threadIdx.x; i < K; i += stride)
        __builtin_nontemporal_store(z, base + i);

    if (blockIdx.x == 0 && (int)threadIdx.x < head + tail) {
        const int t = threadIdx.x;
        const long long e = (t < head) ? (start + t) : (qstart + 4 * K + (t - head));
        out[e] = 0.0f;
    }
}

// Compute-only: block handles rows m0..m0+RPB-1 over all N data points.
// Stores only in-radius hits; counts written directly (rows block-exclusive).
__global__ __launch_bounds__(256) void sparse_kernel(
    const float* __restrict__ data,
    const float* __restrict__ queries,
    const float* __restrict__ radius_p,
    float* __restrict__ out,
    int* __restrict__ counts,
    int N, long long mask_off, long long w_off)
{
    __shared__ float tile[DTILE * 3];
    __shared__ int red[RPB][4];

    const int m0 = blockIdx.x * RPB;
    const int tid = threadIdx.x;

    const float r = radius_p[0];
    const float r2 = __fmul_rn(r, r);

    float qx[RPB], qy[RPB], qz[RPB], qs[RPB];
    long long moff[RPB], woff[RPB];
    #pragma unroll
    for (int j = 0; j < RPB; ++j) {
        const float q0 = queries[3 * (m0 + j) + 0];
        const float q1 = queries[3 * (m0 + j) + 1];
        const float q2 = queries[3 * (m0 + j) + 2];
        qx[j] = q0; qy[j] = q1; qz[j] = q2;
        qs[j] = __fadd_rn(
            __fadd_rn(__fmul_rn(q0, q0), __fmul_rn(q1, q1)), __fmul_rn(q2, q2));
        moff[j] = mask_off + (long long)(m0 + j) * N;
        woff[j] = w_off    + (long long)(m0 + j) * N;
    }
    int cnt[RPB];
    #pragma unroll
    for (int j = 0; j < RPB; ++j) cnt[j] = 0;

    for (int tb = 0; tb < N; tb += DTILE) {
        __syncthreads();  // previous tile's readers done
        {   // coalesced float4 staging: 768 float4s / 256 threads = 3 each
            const float4* src = reinterpret_cast<const float4*>(data + 3LL * tb);
            float4* dst = reinterpret_cast<float4*>(tile);
            #pragma unroll
            for (int k = 0; k < DTILE * 3 / 4 / 256; ++k)
                dst[k * 256 + tid] = src[k * 256 + tid];
        }
        __syncthreads();

        #pragma unroll
        for (int e = 0; e < DTILE / 256; ++e) {  // 4 elements per thread
            const int lo = e * 256 + tid;
            const int n = tb + lo;
            const float d0 = tile[3 * lo + 0];  // stride-3 words: 2 lanes/bank, free
            const float d1 = tile[3 * lo + 1];
            const float d2 = tile[3 * lo + 2];
            const float sqd = __fadd_rn(
                __fadd_rn(__fmul_rn(d0, d0), __fmul_rn(d1, d1)), __fmul_rn(d2, d2));
            #pragma unroll
            for (int j = 0; j < RPB; ++j) {
                const float dot = __fmaf_rn(qz[j], d2,
                                   __fmaf_rn(qy[j], d1, __fmul_rn(qx[j], d0)));
                float v = __fmaf_rn(-2.0f, dot, __fadd_rn(qs[j], sqd));
                v = fmaxf(v, 0.0f);
                if (v <= r2) {       // rare: ~0.26% of lane-iters; execz-skipped
                    out[moff[j] + n] = 1.0f;
                    out[woff[j] + n] = v;
                    ++cnt[j];
                }
            }
        }
    }

    // Per-row block reduction (no atomics; rows exclusive to this block).
    const int wave = tid >> 6, lane = tid & 63;
    #pragma unroll
    for (int j = 0; j < RPB; ++j) {
        int c = cnt[j];
        for (int off = 32; off > 0; off >>= 1) c += __shfl_down(c, off);
        if (lane == 0) red[j][wave] = c;
    }
    __syncthreads();
    if (tid < RPB)
        counts[m0 + tid] = red[tid][0] + red[tid][1] + red[tid][2] + red[tid][3];
}

// Generic fallback (shape assumptions not met): row-owned dense, correct-first.
__global__ __launch_bounds__(256) void nbr_kernel_generic(
    const float* __restrict__ data,
    const float* __restrict__ queries,
    const float* __restrict__ radius_p,
    float* __restrict__ out,
    int* __restrict__ counts,
    int N, long long mask_off, long long w_off)
{
    const int m = blockIdx.x;
    const int tid = threadIdx.x;
    const float r = radius_p[0];
    const float r2 = __fmul_rn(r, r);
    const float q0 = queries[3 * m], q1 = queries[3 * m + 1], q2 = queries[3 * m + 2];
    const float sq_q = __fadd_rn(
        __fadd_rn(__fmul_rn(q0, q0), __fmul_rn(q1, q1)), __fmul_rn(q2, q2));
    float* mask_row = out + mask_off + (long long)m * N;
    float* w_row    = out + w_off    + (long long)m * N;
    int cnt = 0;
    for (int n = tid; n < N; n += 256) {
        const float d0 = data[3 * n], d1 = data[3 * n + 1], d2e = data[3 * n + 2];
        const float sq_d = __fadd_rn(
            __fadd_rn(__fmul_rn(d0, d0), __fmul_rn(d1, d1)), __fmul_rn(d2e, d2e));
        const float dot = __fmaf_rn(q2, d2e, __fmaf_rn(q1, d1, __fmul_rn(q0, d0)));
        float v = __fmaf_rn(-2.0f, dot, __fadd_rn(sq_q, sq_d));
        v = fmaxf(v, 0.0f);
        const bool in = (v <= r2);
        mask_row[n] = in ? 1.0f : 0.0f;
        w_row[n] = in ? v : 0.0f;
        cnt += in ? 1 : 0;
    }
    for (int off = 32; off > 0; off >>= 1) cnt += __shfl_down(cnt, off);
    __shared__ int lds_cnt;
    if (tid == 0) lds_cnt = 0;
    __syncthreads();
    if ((tid & 63) == 0) atomicAdd(&lds_cnt, cnt);
    __syncthreads();
    if (tid == 0) counts[m] = lds_cnt;
}

// Single-block exclusive scan of counts[M] -> row_splits[M+1] (as floats).
__global__ __launch_bounds__(256) void scan_kernel(
    const int* __restrict__ counts, float* __restrict__ out, int M)
{
    __shared__ int sums[256];
    const int t = threadIdx.x;
    const int CH = (M + 255) / 256;  // 48 for M=12288
    const int base = t * CH;

    int local[64];  // CH <= 64 assumed
    int s = 0;
    for (int i = 0; i < CH; ++i) {
        const int v = (base + i < M) ? counts[base + i] : 0;
        local[i] = v;
        s += v;
    }
    sums[t] = s;
    __syncthreads();
    for (int off = 1; off < 256; off <<= 1) {
        const int v = (t >= off) ? sums[t - off] : 0;
        __syncthreads();
        sums[t] += v;
        __syncthreads();
    }
    int prefix = sums[t] - s;  // exclusive prefix of this thread's chunk
    for (int i = 0; i < CH; ++i) {
        if (base + i < M) out[base + i] = (float)prefix;
        prefix += local[i];
    }
    if (t == 255) out[M] = (float)prefix;  // total
}

extern "C" void kernel_launch(void* const* d_in, const int* in_sizes, int n_in,
                              void* d_out, int out_size, void* d_ws, size_t ws_size,
                              hipStream_t stream) {
    const float* data    = (const float*)d_in[0];
    const float* queries = (const float*)d_in[1];
    const float* radius  = (const float*)d_in[2];

    const int N = in_sizes[0] / 3;  // 12288
    const int M = in_sizes[1] / 3;  // 12288

    float* out = (float*)d_out;
    int* counts = (int*)d_ws;

    const long long mask_off = (long long)M + 1;
    const long long w_off = mask_off + (long long)M * N;

    if ((M % RPB == 0) && (N % DTILE == 0) &&
        ws_size >= (size_t)M * sizeof(int)) {
        zero_kernel<<<ZGRID, 256, 0, stream>>>(out, mask_off, 2LL * M * N);
        sparse_kernel<<<M / RPB, 256, 0, stream>>>(data, queries, radius, out,
                                                   counts, N, mask_off, w_off);
    } else {
        nbr_kernel_generic<<<M, 256, 0, stream>>>(data, queries, radius, out,
                                                  counts, N, mask_off, w_off);
    }
    scan_kernel<<<1, 256, 0, stream>>>(counts, out, M);
}